// Round 2
// baseline (444.374 us; speedup 1.0000x reference)
//
#include <hip/hip_runtime.h>
#include <hip/hip_bf16.h>

#define BQ   32768
#define TT   25
#define DIN  4
#define HH   32
#define GG   128
#define NBR  5
#define HIDD 64
#define BT   16     // batch rows per wave
#define WPB  4      // waves per block

using bfrag = __attribute__((ext_vector_type(8))) short;  // 8 bf16 (4 VGPRs)
using accf  = __attribute__((ext_vector_type(4))) float;  // 4 f32 acc

__device__ __forceinline__ float fexp2(float x){
#if __has_builtin(__builtin_amdgcn_exp2f)
  return __builtin_amdgcn_exp2f(x);
#else
  return exp2f(x);
#endif
}
__device__ __forceinline__ float frcpf(float x){
#if __has_builtin(__builtin_amdgcn_rcpf)
  return __builtin_amdgcn_rcpf(x);
#else
  return 1.0f / x;
#endif
}
__device__ __forceinline__ float sigm(float x){
  return frcpf(1.0f + fexp2(-1.442695041f * x));
}
__device__ __forceinline__ float tanh_(float x){
  float t = fexp2(2.885390082f * x);          // e^(2x)
  return 1.0f - 2.0f * frcpf(t + 1.0f);       // (t-1)/(t+1)
}
__device__ __forceinline__ unsigned short fb(float f){  // f32 -> bf16 bits, RNE
  unsigned u = __builtin_bit_cast(unsigned, f);
  u += 0x7fffu + ((u >> 16) & 1u);
  return (unsigned short)(u >> 16);
}
__device__ __forceinline__ bfrag pack8(const float* p){
  bfrag w;
#pragma unroll
  for (int j = 0; j < 8; ++j) w[j] = (short)fb(p[j]);
  return w;
}
__device__ __forceinline__ accf mma(bfrag a, bfrag b, accf c){
  return __builtin_amdgcn_mfma_f32_16x16x32_bf16(a, b, c, 0, 0, 0);
}

// Per-wave LDS (bf16 elems): xbuf [16][25*4] =1600 | h0 [16][40]=640 | h1 640 | fc [16][72]=1152
#define LDSW 4032

__global__ __launch_bounds__(256, 2) void lstm_kernel(
    const float* __restrict__ x,    const float* __restrict__ mask,
    const float* __restrict__ Wih0, const float* __restrict__ Whh0,
    const float* __restrict__ bih0, const float* __restrict__ bhh0,
    const float* __restrict__ Wih1, const float* __restrict__ Whh1,
    const float* __restrict__ bih1, const float* __restrict__ bhh1,
    const float* __restrict__ W1,   const float* __restrict__ b1,
    const float* __restrict__ W2,   const float* __restrict__ b2,
    float* __restrict__ out)
{
  __shared__ __align__(16) unsigned short smem[WPB * LDSW];
  const int tid  = threadIdx.x;
  const int wave = tid >> 6, lane = tid & 63;
  const int col  = lane & 15, quad = lane >> 4;
  const int gwid   = blockIdx.x * WPB + wave;
  const int tile   = gwid & 2047;   // % (BQ/BT)
  const int branch = gwid >> 11;    // / (BQ/BT)
  const int batch0 = tile * BT;
  const int L = (branch + 1) * 5, t0 = TT - L;

  unsigned short* xb  = smem + wave * LDSW;
  unsigned short* h0b = xb + 1600;
  unsigned short* h1b = xb + 2240;
  unsigned short* fcb = xb + 2880;

  // ---- stage xm = x*mask into LDS as bf16 [16 rows][25*4] ----
  for (int i = lane; i < (BT * TT * DIN) / 4; i += 64) {
    int b = i / TT;            // 25 float4 per batch row
    int j = i - b * TT;
    size_t go = (size_t)(batch0 + b) * (TT * DIN) + j * 4;
    float4 xv = *reinterpret_cast<const float4*>(x + go);
    float4 mv = *reinterpret_cast<const float4*>(mask + go);
    ushort4 sv;
    sv.x = fb(xv.x * mv.x); sv.y = fb(xv.y * mv.y);
    sv.z = fb(xv.z * mv.z); sv.w = fb(xv.w * mv.w);
    *reinterpret_cast<ushort4*>(xb + b * (TT * DIN) + j * 4) = sv;
  }

  // ---- weights -> B-layout bf16 fragments in VGPRs ----
  const float* Wih0p = Wih0 + branch * GG * DIN;
  const float* Whh0p = Whh0 + branch * GG * HH;
  const float* Wih1p = Wih1 + branch * GG * HH;
  const float* Whh1p = Whh1 + branch * GG * HH;
  const float* bi0p = bih0 + branch * GG;
  const float* bh0p = bhh0 + branch * GG;
  const float* bi1p = bih1 + branch * GG;
  const float* bh1p = bhh1 + branch * GG;

  bfrag Bx0[8], Bh0[8], Bi1[8], Bh1[8];
  float bias0[8], bias1[8];
#pragma unroll
  for (int nt = 0; nt < 8; ++nt) {
    const int g = nt * 16 + col;                 // gate index (N dim)
    bias0[nt] = bi0p[g] + bh0p[g];
    bias1[nt] = bi1p[g] + bh1p[g];
    Bh0[nt] = pack8(Whh0p + g * HH + quad * 8);  // B[k=quad*8+j][n=g]
    Bi1[nt] = pack8(Wih1p + g * HH + quad * 8);
    Bh1[nt] = pack8(Whh1p + g * HH + quad * 8);
    bfrag bx = {0,0,0,0,0,0,0,0};                // K=32, only k<4 nonzero
    if (quad == 0) {
      const float* q = Wih0p + g * DIN;
      bx[0] = (short)fb(q[0]); bx[1] = (short)fb(q[1]);
      bx[2] = (short)fb(q[2]); bx[3] = (short)fb(q[3]);
    }
    Bx0[nt] = bx;
  }
  __syncthreads();   // xb staged

  bfrag aH0 = {0,0,0,0,0,0,0,0}, aH1 = {0,0,0,0,0,0,0,0};
  accf c0[2] = {{0,0,0,0},{0,0,0,0}}, c1[2] = {{0,0,0,0},{0,0,0,0}};

  for (int s = 0; s < L; ++s) {
    const int t = t0 + s;
    accf acc[8];
    // ---------- layer 0 : gates = x@Wih0T + h0@Whh0T + b ----------
#pragma unroll
    for (int nt = 0; nt < 8; ++nt) acc[nt] = (accf){bias0[nt], bias0[nt], bias0[nt], bias0[nt]};
    bfrag ax = {0,0,0,0,0,0,0,0};
    if (quad == 0) {   // A[m=col][k=j], k<4 = x, rest zero
      ushort4 xv = *reinterpret_cast<const ushort4*>(xb + col * (TT * DIN) + t * 4);
      ax[0] = (short)xv.x; ax[1] = (short)xv.y; ax[2] = (short)xv.z; ax[3] = (short)xv.w;
    }
#pragma unroll
    for (int nt = 0; nt < 8; ++nt) acc[nt] = mma(ax, Bx0[nt], acc[nt]);
#pragma unroll
    for (int nt = 0; nt < 8; ++nt) acc[nt] = mma(aH0, Bh0[nt], acc[nt]);
    // activations: nt = gatetype*2 + ut ; i=0,1 f=2,3 g=4,5 o=6,7
#pragma unroll
    for (int ut = 0; ut < 2; ++ut) {
#pragma unroll
      for (int r = 0; r < 4; ++r) {
        float c = c0[ut][r];
        c = sigm(acc[2 + ut][r]) * c + sigm(acc[ut][r]) * tanh_(acc[4 + ut][r]);
        c0[ut][r] = c;
        float h = sigm(acc[6 + ut][r]) * tanh_(c);
        h0b[(quad * 4 + r) * 40 + ut * 16 + col] = fb(h);   // C-layout -> LDS
      }
    }
    __syncthreads();
    aH0 = *reinterpret_cast<const bfrag*>(h0b + col * 40 + quad * 8);  // A-layout
    // ---------- layer 1 : gates = h0@Wih1T + h1@Whh1T + b ----------
#pragma unroll
    for (int nt = 0; nt < 8; ++nt) acc[nt] = (accf){bias1[nt], bias1[nt], bias1[nt], bias1[nt]};
#pragma unroll
    for (int nt = 0; nt < 8; ++nt) acc[nt] = mma(aH0, Bi1[nt], acc[nt]);
#pragma unroll
    for (int nt = 0; nt < 8; ++nt) acc[nt] = mma(aH1, Bh1[nt], acc[nt]);
#pragma unroll
    for (int ut = 0; ut < 2; ++ut) {
#pragma unroll
      for (int r = 0; r < 4; ++r) {
        float c = c1[ut][r];
        c = sigm(acc[2 + ut][r]) * c + sigm(acc[ut][r]) * tanh_(acc[4 + ut][r]);
        c1[ut][r] = c;
        float h = sigm(acc[6 + ut][r]) * tanh_(c);
        h1b[(quad * 4 + r) * 40 + ut * 16 + col] = fb(h);
      }
    }
    __syncthreads();
    aH1 = *reinterpret_cast<const bfrag*>(h1b + col * 40 + quad * 8);
  }

  // ---- MLP head: tmp = gelu(h1@W1T + b1); out = tmp@W2T + b2 ----
  accf t1[4];
  bfrag Bw1[4];
#pragma unroll
  for (int nt = 0; nt < 4; ++nt) {
    const int n = nt * 16 + col;
    Bw1[nt] = pack8(W1 + n * HH + quad * 8);
    t1[nt] = (accf){b1[n], b1[n], b1[n], b1[n]};
  }
#pragma unroll
  for (int nt = 0; nt < 4; ++nt) t1[nt] = mma(aH1, Bw1[nt], t1[nt]);
#pragma unroll
  for (int nt = 0; nt < 4; ++nt) {
#pragma unroll
    for (int r = 0; r < 4; ++r) {
      float v = t1[nt][r];
      v = 0.5f * v * (1.0f + erff(v * 0.70710678f));      // exact gelu
      fcb[(quad * 4 + r) * 72 + nt * 16 + col] = fb(v);
    }
  }
  __syncthreads();
  bfrag af0 = *reinterpret_cast<const bfrag*>(fcb + col * 72 + quad * 8);       // k 0..31
  bfrag af1 = *reinterpret_cast<const bfrag*>(fcb + col * 72 + 32 + quad * 8);  // k 32..63
  accf o[4];
  bfrag Bw2a[4], Bw2b[4];
#pragma unroll
  for (int nt = 0; nt < 4; ++nt) {
    const int n = nt * 16 + col;
    Bw2a[nt] = pack8(W2 + n * HIDD + quad * 8);
    Bw2b[nt] = pack8(W2 + n * HIDD + 32 + quad * 8);
    o[nt] = (accf){b2[n], b2[n], b2[n], b2[n]};
  }
#pragma unroll
  for (int nt = 0; nt < 4; ++nt) {
    o[nt] = mma(af0, Bw2a[nt], o[nt]);
    o[nt] = mma(af1, Bw2b[nt], o[nt]);
  }
  // ---- store f32 output: out[(batch, branch, n)] ----
#pragma unroll
  for (int nt = 0; nt < 4; ++nt) {
#pragma unroll
    for (int r = 0; r < 4; ++r) {
      const int row = quad * 4 + r;
      out[(size_t)((batch0 + row) * NBR + branch) * HIDD + nt * 16 + col] = o[nt][r];
    }
  }
}

extern "C" void kernel_launch(void* const* d_in, const int* in_sizes, int n_in,
                              void* d_out, int out_size, void* d_ws, size_t ws_size,
                              hipStream_t stream) {
  const float* x    = (const float*)d_in[0];
  const float* mask = (const float*)d_in[1];
  const float* Wih0 = (const float*)d_in[2];
  const float* Whh0 = (const float*)d_in[3];
  const float* bih0 = (const float*)d_in[4];
  const float* bhh0 = (const float*)d_in[5];
  const float* Wih1 = (const float*)d_in[6];
  const float* Whh1 = (const float*)d_in[7];
  const float* bih1 = (const float*)d_in[8];
  const float* bhh1 = (const float*)d_in[9];
  const float* W1   = (const float*)d_in[10];
  const float* b1   = (const float*)d_in[11];
  const float* W2   = (const float*)d_in[12];
  const float* b2   = (const float*)d_in[13];
  float* out = (float*)d_out;

  const int nblocks = (BQ / BT) * NBR / WPB;   // 2560
  lstm_kernel<<<nblocks, 256, 0, stream>>>(x, mask, Wih0, Whh0, bih0, bhh0,
                                           Wih1, Whh1, bih1, bhh1, W1, b1, W2, b2, out);
}